// Round 7
// baseline (1065.889 us; speedup 1.0000x reference)
//
#include <hip/hip_runtime.h>

#define B_ 64
#define T_ 2000
#define V_ 512
#define L_ 200
#define NCONS 128          // 64 batches x {fwd, bwd} consumer blocks (1 active wave each)
#define NJB 63             // j-blocks per batch: 63*4 = 252 >= max nch (250)
#define NPRODB (B_ * NJB)  // 4032 producer blocks, 4 waves = 4 chunks each

// Split CTC v2. Round-6 post-mortem: producer blocks cost ~30K cy each
// (1-wave blocks + every data store agent-scope write-through + per-block
// vmcnt(0) drain of 66 L3 acks) -> producers ran at ~1 TB/s, 5x over the
// 42us BW floor, and consumers (whose last chunks are the last producer
// blocks) inherited that. Fix: 4-wave producer blocks (one chunk per wave,
// COMPACT once per block), PLAIN L2-cached data stores, and ONE
// __ATOMIC_RELEASE agent flag store per chunk (compiler emits the single
// buffer_wbl2 sc1 writeback). Consumer path is byte-identical to the
// round-6-verified version (relaxed agent flag poll -> control-dependent
// sc1 data loads, 4-chunk data prefetch, 2-deep flag prefetch).

typedef _Float16 half4 __attribute__((ext_vector_type(4)));
union H4U { unsigned long long u; half4 h; float2 f2; };

__device__ __forceinline__ float dpp_shr1_f(float x) {  // lane i <- lane i-1; lane0 <- 0
  return __int_as_float(__builtin_amdgcn_update_dpp(0, __float_as_int(x), 0x138, 0xf, 0xf, true));
}
__device__ __forceinline__ int dpp_shr1_i(int x) {
  return __builtin_amdgcn_update_dpp(0, x, 0x138, 0xf, 0xf, true);
}
__device__ __forceinline__ float dpp_shl1_f(float x) {  // lane i <- lane i+1; lane63 <- 0
  return __int_as_float(__builtin_amdgcn_update_dpp(0, __float_as_int(x), 0x130, 0xf, 0xf, true));
}
__device__ __forceinline__ int dpp_shl1_i(int x) {
  return __builtin_amdgcn_update_dpp(0, x, 0x130, 0xf, 0xf, true);
}
#define DPPADD(v, ctrl, rmask)                                                              \
  v += __int_as_float(__builtin_amdgcn_update_dpp(0, __float_as_int(v), ctrl, rmask, 0xf, true));

__device__ __forceinline__ int ldflag(const int* p) {
  return __hip_atomic_load(p, __ATOMIC_RELAXED, __HIP_MEMORY_SCOPE_AGENT);
}

__global__ __launch_bounds__(64) void kflags(int* __restrict__ flags) {
  const int base = blockIdx.x * 256 + threadIdx.x;
  flags[base] = 0; flags[base + 64] = 0; flags[base + 128] = 0; flags[base + 192] = 0;
}

__global__ __launch_bounds__(256, 2) void ctc_split(
    const float* __restrict__ logits, const int* __restrict__ lens,
    const int* __restrict__ targets, unsigned long long* __restrict__ cull,
    unsigned long long* __restrict__ bull, int* __restrict__ flags,
    float* __restrict__ AF, int* __restrict__ EF,
    float* __restrict__ DD, int* __restrict__ EB) {
  const int tid = threadIdx.x;
  const int wid = tid >> 6;
  const int lane = tid & 63;
  __shared__ int cmp[256];
  __shared__ __align__(16) float scr[4][2][512];  // per-producer-wave exp scratch

#define COMPACT(BB)                                                          \
  int base = 0;                                                              \
  {                                                                          \
    cmp[lane] = 0; cmp[64 + lane] = 0; cmp[128 + lane] = 0; cmp[192 + lane] = 0; \
    _Pragma("unroll") for (int cc = 0; cc < 4; ++cc) {                       \
      const int l = cc * 64 + lane;                                          \
      const int v = (l < L_) ? targets[(BB) * L_ + l] : 0;                   \
      const unsigned long long mk = __ballot(v != 0);                        \
      const int pos = base + __popcll(mk & ((1ull << lane) - 1ull));         \
      if (v != 0) cmp[pos] = v;                                              \
      base += __popcll(mk);                                                  \
    }                                                                        \
    asm volatile("s_waitcnt lgkmcnt(0)" ::: "memory");                       \
  }

  if ((int)blockIdx.x >= NCONS) {
    // ============ producer block: batch b, 4 waves = chunks j..j+3 ============
    const int g = blockIdx.x - NCONS;
    const int b = g & 63;
    const int jb = g >> 6;
    const int len = lens[b];
    const int nch = (len + 7) >> 3;
    if (wid == 0) { COMPACT(b); }
    __syncthreads();
    const int j = jb * 4 + wid;  // delivery priority: interleave both ends
    if (j < nch) {
      const int c = (j & 1) ? (nch - 1 - (j >> 1)) : (j >> 1);
      const int4 c4 = *(const int4*)(&cmp[4 * lane]);
      const int l0 = 4 * lane;
      const bool v0 = l0 + 0 < L_, v1 = l0 + 1 < L_, v2 = l0 + 2 < L_, v3 = l0 + 3 < L_;

      const float* rowp = logits + (size_t)b * (T_ * V_) + (size_t)c * (8 * V_);
      float4 X[16];
#pragma unroll
      for (int r = 0; r < 8; ++r) {  // issue all row loads up front
        X[2 * r] = *(const float4*)(rowp + r * V_ + 4 * lane);
        X[2 * r + 1] = *(const float4*)(rowp + r * V_ + 256 + 4 * lane);
      }
      const size_t obase = ((size_t)(b * T_ + c * 8)) * 64 + lane;
#pragma unroll
      for (int r = 0; r < 8; ++r) {
        const float4 xe = X[2 * r], xo = X[2 * r + 1];
        const float e0 = __expf(xe.x), e1 = __expf(xe.y), e2 = __expf(xe.z), e3 = __expf(xe.w);
        const float e4 = __expf(xo.x), e5 = __expf(xo.y), e6 = __expf(xo.z), e7 = __expf(xo.w);
        float s = ((e0 + e1) + (e2 + e3)) + ((e4 + e5) + (e6 + e7));
        DPPADD(s, 0x111, 0xf); DPPADD(s, 0x112, 0xf); DPPADD(s, 0x114, 0xf);
        DPPADD(s, 0x118, 0xf); DPPADD(s, 0x142, 0xa); DPPADD(s, 0x143, 0xc);
        const float sum = __int_as_float(__builtin_amdgcn_readlane(__float_as_int(s), 63));
        const float inv = 32.0f / sum;  // same x32 prescale as verified kernels
        float* sc = &scr[wid][r & 1][0];  // 2-slot alternation; wave-ordered LDS
        *(float4*)(sc + 4 * lane) = make_float4(e0, e1, e2, e3);
        *(float4*)(sc + 256 + 4 * lane) = make_float4(e4, e5, e6, e7);
        asm volatile("s_waitcnt lgkmcnt(0)" ::: "memory");
        H4U p;
        p.h.x = (_Float16)(v0 ? sc[c4.x] * inv : 0.0f);
        p.h.y = (_Float16)(v1 ? sc[c4.y] * inv : 0.0f);
        p.h.z = (_Float16)(v2 ? sc[c4.z] * inv : 0.0f);
        p.h.w = (_Float16)(v3 ? sc[c4.w] * inv : 0.0f);
        cull[obase + (size_t)r * 64] = p.u;  // plain L2-cached store
        if (lane == 0)
          ((unsigned*)bull)[b * 2048 + c * 8 + r] = __float_as_uint(e0 * inv);
      }
      // RELEASE: one agent-scope flag store; compiler emits vmcnt drain +
      // buffer_wbl2 sc1 (single L2 writeback) before the sc1 flag store.
      if (lane == 0)
        __hip_atomic_store(flags + b * 256 + c, 1, __ATOMIC_RELEASE, __HIP_MEMORY_SCOPE_AGENT);
    }
    return;
  }

  // ======================= consumer block (wave 0 only) =======================
  if (wid != 0) return;
  const int b = blockIdx.x >> 1;
  const int dirb = blockIdx.x & 1;
  const int len = lens[b];
  const int rem = len & 7;
  const int nch = (len + 7) >> 3;
  const int Cf = nch >> 1;  // fwd owns chunks [0, Cf) (all full); bwd owns [Cf, nch)
  const int Ntot = dirb ? (nch - Cf) : Cf;
  const int c0v = dirb ? (nch - 1) : 0;
  const int dstep = dirb ? -1 : 1;
#define CHK(J) (c0v + dstep * (J))

  COMPACT(b);
  const int tl = base;
  const int4 c4 = *(const int4*)(&cmp[4 * lane]);

  const int cm1 = __shfl_up(c4.w, 1);
  const float m0 = (lane > 0 && c4.x != 0 && c4.x != cm1) ? 1.0f : 0.0f;
  const float m1 = (c4.y != 0 && c4.y != c4.x) ? 1.0f : 0.0f;
  const float m2 = (c4.z != 0 && c4.z != c4.y) ? 1.0f : 0.0f;
  const float m3 = (c4.w != 0 && c4.w != c4.z) ? 1.0f : 0.0f;
  const float m0n = dpp_shl1_f(m0);

  float a0 = 0.f, a1 = 0.f, a2 = 0.f, a3 = 0.f, a4 = 0.f, a5 = 0.f, a6 = 0.f, a7 = 0.f;
  int E = 0;
  float fac = 1.0f;
  if (!dirb) {
    if (lane == 0) a0 = 1.0f;  // chunk-0 step u=0 reproduces the alpha init
  } else {
    const int st = 2 * tl;  // gamma seed; first bwd step reproduces the init
    if (lane == (st >> 3)) {
      const int e = st & 7;
      a0 = (e == 0) ? 1.0f : 0.0f; a1 = (e == 1) ? 1.0f : 0.0f;
      a2 = (e == 2) ? 1.0f : 0.0f; a3 = (e == 3) ? 1.0f : 0.0f;
      a4 = (e == 4) ? 1.0f : 0.0f; a5 = (e == 5) ? 1.0f : 0.0f;
      a6 = (e == 6) ? 1.0f : 0.0f; a7 = (e == 7) ? 1.0f : 0.0f;
    }
  }
  __builtin_amdgcn_s_setprio(1);  // consumer wave is the critical path on its CU

  unsigned long long LB0[8], LB1[8], LB2[8], LB3[8];
  float4 BLa0, BLb0, BLa1, BLb1, BLa2, BLb2, BLa3, BLb3;

#define POLL(CIDX)                                                           \
  {                                                                          \
    int* fp_ = flags + b * 256 + (CIDX);                                     \
    while (ldflag(fp_) == 0) __builtin_amdgcn_s_sleep(2);                    \
    asm volatile("" ::: "memory");                                           \
  }

#define LOADC(S, CIDX)                                                       \
  {                                                                          \
    const int c_ = (CIDX);                                                   \
    const size_t base_ = ((size_t)(b * T_ + c_ * 8)) * 64 + lane;            \
    _Pragma("unroll") for (int u = 0; u < 8; ++u)                            \
        LB##S[u] = __hip_atomic_load(cull + base_ + (size_t)u * 64,          \
                                     __ATOMIC_RELAXED, __HIP_MEMORY_SCOPE_AGENT); \
    const size_t bb_ = (size_t)b * 1024 + (size_t)c_ * 4;                    \
    H4U t0_, t1_, t2_, t3_;                                                  \
    t0_.u = __hip_atomic_load(bull + bb_ + 0, __ATOMIC_RELAXED, __HIP_MEMORY_SCOPE_AGENT); \
    t1_.u = __hip_atomic_load(bull + bb_ + 1, __ATOMIC_RELAXED, __HIP_MEMORY_SCOPE_AGENT); \
    t2_.u = __hip_atomic_load(bull + bb_ + 2, __ATOMIC_RELAXED, __HIP_MEMORY_SCOPE_AGENT); \
    t3_.u = __hip_atomic_load(bull + bb_ + 3, __ATOMIC_RELAXED, __HIP_MEMORY_SCOPE_AGENT); \
    BLa##S = make_float4(t0_.f2.x, t0_.f2.y, t1_.f2.x, t1_.f2.y);            \
    BLb##S = make_float4(t2_.f2.x, t2_.f2.y, t3_.f2.x, t3_.f2.y);            \
  }

// After STEP8 of chunk i: ensure flag for nx=i+4 (prefetched in nf0; spin
// only if producer behind), load its data, rotate the 2-deep flag pipeline.
#define PREFETCH(S)                                                          \
  {                                                                          \
    const int nx_ = i + 4;                                                   \
    if (nx_ < Ntot) {                                                        \
      if (nf0 == 0) POLL(CHK(nx_));                                          \
      LOADC(S, CHK(nx_));                                                    \
      nf0 = nf1;                                                             \
      const int n2_ = nx_ + 2;                                               \
      nf1 = (n2_ < Ntot) ? ldflag(flags + b * 256 + CHK(n2_)) : 1;           \
    }                                                                        \
  }

#define STEP8F(S)                                                            \
  {                                                                          \
    const float blv_[8] = {BLa##S.x, BLa##S.y, BLa##S.z, BLa##S.w,           \
                           BLb##S.x, BLb##S.y, BLb##S.z, BLb##S.w};          \
    _Pragma("unroll") for (int u = 0; u < 8; ++u) {                          \
      H4U q_; q_.u = LB##S[u];                                               \
      const float qx = (float)q_.h.x, qy = (float)q_.h.y;                    \
      const float qz = (float)q_.h.z, qw = (float)q_.h.w;                    \
      const float pbv = blv_[u];                                             \
      const float s1 = dpp_shr1_f(a7) * fac;  /* lane0 -> 0 */               \
      float n0 = (a0 + s1) * pbv;                                            \
      float n1 = fmaf(m0, s1, a0 + a1) * qx;                                 \
      float n2 = (a2 + a1) * pbv;                                            \
      float n3 = fmaf(m1, a1, a2 + a3) * qy;                                 \
      float n4 = (a4 + a3) * pbv;                                            \
      float n5 = fmaf(m2, a3, a4 + a5) * qz;                                 \
      float n6 = (a6 + a5) * pbv;                                            \
      float n7 = fmaf(m3, a5, a6 + a7) * qw;                                 \
      a0 = n0; a1 = n1; a2 = n2; a3 = n3;                                    \
      a4 = n4; a5 = n5; a6 = n6; a7 = n7;                                    \
    }                                                                        \
  }

#define STEP8B(S, UHI)                                                       \
  {                                                                          \
    const float blv_[8] = {BLa##S.x, BLa##S.y, BLa##S.z, BLa##S.w,           \
                           BLb##S.x, BLb##S.y, BLb##S.z, BLb##S.w};          \
    _Pragma("unroll") for (int u = 7; u >= 0; --u) {                         \
      if (u <= (UHI)) {                                                      \
        H4U q_; q_.u = LB##S[u];                                             \
        const float qx = (float)q_.h.x, qy = (float)q_.h.y;                  \
        const float qz = (float)q_.h.z, qw = (float)q_.h.w;                  \
        const float pbv = blv_[u];                                           \
        const float sa = dpp_shl1_f(a0) * fac;  /* lane63 -> 0 */            \
        const float sb = dpp_shl1_f(a1) * fac;                               \
        float n0 = (a0 + a1) * pbv;                                          \
        float n1 = fmaf(m1, a3, a1 + a2) * qx;                               \
        float n2 = (a2 + a3) * pbv;                                          \
        float n3 = fmaf(m2, a5, a3 + a4) * qy;                               \
        float n4 = (a4 + a5) * pbv;                                          \
        float n5 = fmaf(m3, a7, a5 + a6) * qz;                               \
        float n6 = (a6 + a7) * pbv;                                          \
        float n7 = fmaf(m0n, sb, a7 + sa) * qw;                              \
        a0 = n0; a1 = n1; a2 = n2; a3 = n3;                                  \
        a4 = n4; a5 = n5; a6 = n6; a7 = n7;                                  \
      }                                                                      \
    }                                                                        \
  }

#define RENORM_COMMON                                                        \
    const float mx = fmaxf(fmaxf(fmaxf(a0, a1), fmaxf(a2, a3)),              \
                           fmaxf(fmaxf(a4, a5), fmaxf(a6, a7)));             \
    const bool dead = (mx == 0.0f);                                          \
    int e_ = (int)((__float_as_uint(mx) >> 23) & 0xff) - 127;                \
    if (dead) e_ = 0;                                                        \
    const float sc_ = __int_as_float((unsigned)(127 - e_) << 23);            \
    a0 *= sc_; a1 *= sc_; a2 *= sc_; a3 *= sc_;                              \
    a4 *= sc_; a5 *= sc_; a6 *= sc_; a7 *= sc_;                              \
    const int En_ = E + e_;

#define RENORMF                                                              \
  {                                                                          \
    RENORM_COMMON                                                            \
    const int EnP_ = dpp_shr1_i(En_);                                        \
    E = dead ? EnP_ : En_;                                                   \
    const int Ep_ = dpp_shr1_i(E);                                           \
    const int d_ = Ep_ - E;                                                  \
    int dc_ = d_ < -126 ? -126 : (d_ > 126 ? 126 : d_);                      \
    fac = (d_ < -126) ? 0.0f : __int_as_float((unsigned)(dc_ + 127) << 23);  \
  }

#define RENORMB                                                              \
  {                                                                          \
    RENORM_COMMON                                                            \
    const int EnP_ = dpp_shl1_i(En_);                                        \
    E = dead ? EnP_ : En_;                                                   \
    const int Ep_ = dpp_shl1_i(E);                                           \
    const int d_ = Ep_ - E;                                                  \
    int dc_ = d_ < -126 ? -126 : (d_ > 126 ? 126 : d_);                      \
    fac = (d_ < -126) ? 0.0f : __int_as_float((unsigned)(dc_ + 127) << 23);  \
  }

  // prologue: spin-load first 4 chunks, prime 2-deep flag prefetch
  POLL(CHK(0)); LOADC(0, CHK(0));
  POLL(CHK(1)); LOADC(1, CHK(1));
  POLL(CHK(2)); LOADC(2, CHK(2));
  POLL(CHK(3)); LOADC(3, CHK(3));
  int nf0 = (4 < Ntot) ? ldflag(flags + b * 256 + CHK(4)) : 1;
  int nf1 = (5 < Ntot) ? ldflag(flags + b * 256 + CHK(5)) : 1;

  if (!dirb) {
    for (int i = 0; i < Ntot; ++i) {
      switch (i & 3) {
        case 0: STEP8F(0); RENORMF; PREFETCH(0); break;
        case 1: STEP8F(1); RENORMF; PREFETCH(1); break;
        case 2: STEP8F(2); RENORMF; PREFETCH(2); break;
        default: STEP8F(3); RENORMF; PREFETCH(3); break;
      }
    }
    *(float4*)(AF + b * 512 + lane * 8) = make_float4(a0, a1, a2, a3);
    *(float4*)(AF + b * 512 + lane * 8 + 4) = make_float4(a4, a5, a6, a7);
    EF[b * 64 + lane] = E;
  } else {
    for (int i = 0; i < Ntot; ++i) {
      const int uh = (i == 0 && rem) ? (rem - 1) : 7;  // masked tail consumed first
      switch (i & 3) {
        case 0: STEP8B(0, uh); RENORMB; PREFETCH(0); break;
        case 1: STEP8B(1, uh); RENORMB; PREFETCH(1); break;
        case 2: STEP8B(2, uh); RENORMB; PREFETCH(2); break;
        default: STEP8B(3, uh); RENORMB; PREFETCH(3); break;
      }
    }
    // delta = one emission-less backward step of gamma_{8Cf}
    const float sa = dpp_shl1_f(a0) * fac;
    const float sb = dpp_shl1_f(a1) * fac;
    const float d0 = a0 + a1;
    const float d1 = fmaf(m1, a3, a1 + a2);
    const float d2 = a2 + a3;
    const float d3 = fmaf(m2, a5, a3 + a4);
    const float d4 = a4 + a5;
    const float d5 = fmaf(m3, a7, a5 + a6);
    const float d6 = a6 + a7;
    const float d7 = fmaf(m0n, sb, a7 + sa);
    *(float4*)(DD + b * 512 + lane * 8) = make_float4(d0, d1, d2, d3);
    *(float4*)(DD + b * 512 + lane * 8 + 4) = make_float4(d4, d5, d6, d7);
    EB[b * 64 + lane] = E;
  }
#undef POLL
#undef LOADC
#undef PREFETCH
#undef STEP8F
#undef STEP8B
#undef RENORM_COMMON
#undef RENORMF
#undef RENORMB
#undef COMPACT
#undef CHK
}

// ---- splice + final sum: out = -sum_b log( sum_s alpha[s]*delta[s] ) + len*ln(32) ----
__global__ __launch_bounds__(512) void kcomb(const int* __restrict__ lens,
                                             const float* __restrict__ AF,
                                             const int* __restrict__ EF,
                                             const float* __restrict__ DD,
                                             const int* __restrict__ EB,
                                             float* __restrict__ out) {
  const int wid = threadIdx.x >> 6;
  const int lane = threadIdx.x & 63;
  __shared__ float part[8];
  float acc = 0.0f;
#pragma unroll
  for (int q = 0; q < 8; ++q) {
    const int b = wid * 8 + q;
    const float4 f0 = *(const float4*)(AF + b * 512 + lane * 8);
    const float4 f1 = *(const float4*)(AF + b * 512 + lane * 8 + 4);
    const float4 g0 = *(const float4*)(DD + b * 512 + lane * 8);
    const float4 g1 = *(const float4*)(DD + b * 512 + lane * 8 + 4);
    const float dot = ((f0.x * g0.x + f0.y * g0.y) + (f0.z * g0.z + f0.w * g0.w)) +
                      ((f1.x * g1.x + f1.y * g1.y) + (f1.z * g1.z + f1.w * g1.w));
    const int Es = EF[b * 64 + lane] + EB[b * 64 + lane];
    const bool z = (dot == 0.0f);
    int Ek = z ? (-(1 << 28)) : Es;
#pragma unroll
    for (int off = 32; off; off >>= 1) {
      const int o = __shfl_xor(Ek, off);
      Ek = o > Ek ? o : Ek;
    }
    float v = z ? 0.0f : ldexpf(dot, Es - Ek);
#pragma unroll
    for (int off = 32; off; off >>= 1) v += __shfl_xor(v, off);
    const float ll = __logf(v) + (float)Ek * 0.69314718056f - (float)lens[b] * 3.46573590280f;
    acc -= ll;
  }
  if (lane == 0) part[wid] = acc;
  __syncthreads();
  if (threadIdx.x == 0) {
    float s = ((part[0] + part[1]) + (part[2] + part[3])) +
              ((part[4] + part[5]) + (part[6] + part[7]));
    out[0] = s;
  }
}

extern "C" void kernel_launch(void* const* d_in, const int* in_sizes, int n_in,
                              void* d_out, int out_size, void* d_ws, size_t ws_size,
                              hipStream_t stream) {
  const float* logits = (const float*)d_in[0];     // [B,T,V] fp32 — read-only
  const int* input_lengths = (const int*)d_in[1];  // [B]
  const int* targets = (const int*)d_in[2];        // [B,L]
  float* out = (float*)d_out;                      // [1]
  // ws layout (bytes): compact fp16 [B][T][256] = 65,536,000; blank f32 [B][2048]
  // = 524,288; flags int [B][256] = 65,536; AF/EF/DD/EB.
  unsigned long long* cull = (unsigned long long*)d_ws;
  unsigned long long* bull = (unsigned long long*)((char*)d_ws + 65536000);
  int* flags = (int*)((char*)d_ws + 66060288);
  float* AF = (float*)((char*)d_ws + 66125824);
  int* EF = (int*)((char*)d_ws + 66256896);
  float* DD = (float*)((char*)d_ws + 66273280);
  int* EB = (int*)((char*)d_ws + 66404352);
  (void)in_sizes; (void)n_in; (void)out_size; (void)ws_size;

  kflags<<<B_, 64, 0, stream>>>(flags);
  ctc_split<<<NCONS + NPRODB, 256, 0, stream>>>(logits, input_lengths, targets,
                                                cull, bull, flags, AF, EF, DD, EB);
  kcomb<<<1, 512, 0, stream>>>(input_lengths, AF, EF, DD, EB, out);
}

// Round 8
// 479.329 us; speedup vs baseline: 2.2237x; 2.2237x over previous
//
#include <hip/hip_runtime.h>

#define B_ 64
#define T_ 2000
#define V_ 512
#define L_ 200
#define NJB 63  // j-blocks per batch in kprob: 63*4 waves = 252 >= max nch (250)

// Two-phase CTC, zero inter-block synchronization (stream-ordered kernels).
// Rounds 5-7 showed flag/atomic overlap schemes cost more than they buy
// (agent-scope write-through: 230us; RELEASE buffer_wbl2 per chunk: 797us).
// Phase A (kprob): ordinary full-occupancy memory-bound kernel - softmax sum
//   via DPP, label gather via per-wave LDS scratch, write compact fp16 probs
//   (512 B/step) + blank f32, PLAIN cached stores. 4032 blocks x 4 waves.
// Phase B (krec): 128 one-wave blocks (64 batches x fwd/bwd), the verified
//   block-floating-point recursions, PLAIN cached loads (visibility via
//   dispatch boundary), 4-chunk register prefetch. Splice P = alpha . delta
//   combined in kcomb (plain store, no atomics anywhere).

typedef _Float16 half4 __attribute__((ext_vector_type(4)));
union H4U { unsigned long long u; half4 h; float2 f2; };

__device__ __forceinline__ float dpp_shr1_f(float x) {  // lane i <- lane i-1; lane0 <- 0
  return __int_as_float(__builtin_amdgcn_update_dpp(0, __float_as_int(x), 0x138, 0xf, 0xf, true));
}
__device__ __forceinline__ int dpp_shr1_i(int x) {
  return __builtin_amdgcn_update_dpp(0, x, 0x138, 0xf, 0xf, true);
}
__device__ __forceinline__ float dpp_shl1_f(float x) {  // lane i <- lane i+1; lane63 <- 0
  return __int_as_float(__builtin_amdgcn_update_dpp(0, __float_as_int(x), 0x130, 0xf, 0xf, true));
}
__device__ __forceinline__ int dpp_shl1_i(int x) {
  return __builtin_amdgcn_update_dpp(0, x, 0x130, 0xf, 0xf, true);
}
#define DPPADD(v, ctrl, rmask)                                                              \
  v += __int_as_float(__builtin_amdgcn_update_dpp(0, __float_as_int(v), ctrl, rmask, 0xf, true));

#define COMPACT(BB)                                                          \
  int base = 0;                                                              \
  {                                                                          \
    cmp[lane] = 0; cmp[64 + lane] = 0; cmp[128 + lane] = 0; cmp[192 + lane] = 0; \
    _Pragma("unroll") for (int cc = 0; cc < 4; ++cc) {                       \
      const int l = cc * 64 + lane;                                          \
      const int v = (l < L_) ? targets[(BB) * L_ + l] : 0;                   \
      const unsigned long long mk = __ballot(v != 0);                        \
      const int pos = base + __popcll(mk & ((1ull << lane) - 1ull));         \
      if (v != 0) cmp[pos] = v;                                              \
      base += __popcll(mk);                                                  \
    }                                                                        \
    asm volatile("s_waitcnt lgkmcnt(0)" ::: "memory");                       \
  }

// ================== phase A: softmax + gather -> compact fp16 ==================
__global__ __launch_bounds__(256, 4) void kprob(const float* __restrict__ logits,
                                                const int* __restrict__ lens,
                                                const int* __restrict__ targets,
                                                unsigned long long* __restrict__ cull,
                                                float* __restrict__ bl) {
  const int tid = threadIdx.x;
  const int wid = tid >> 6;
  const int lane = tid & 63;
  __shared__ int cmp[256];
  __shared__ __align__(16) float scr[4][2][512];  // per-wave exp scratch

  const int g = blockIdx.x;
  const int b = g & 63;
  const int jb = g >> 6;
  const int len = lens[b];
  const int nch = (len + 7) >> 3;
  if (wid == 0) { COMPACT(b); }
  __syncthreads();
  const int c = jb * 4 + wid;  // this wave's 8-step chunk
  if (c >= nch) return;

  const int4 c4 = *(const int4*)(&cmp[4 * lane]);
  const int l0 = 4 * lane;
  const bool v0 = l0 + 0 < L_, v1 = l0 + 1 < L_, v2 = l0 + 2 < L_, v3 = l0 + 3 < L_;

  const float* rowp = logits + (size_t)b * (T_ * V_) + (size_t)c * (8 * V_);
  float4 X[16];
#pragma unroll
  for (int r = 0; r < 8; ++r) {  // issue all row loads up front
    X[2 * r] = *(const float4*)(rowp + r * V_ + 4 * lane);
    X[2 * r + 1] = *(const float4*)(rowp + r * V_ + 256 + 4 * lane);
  }
  const size_t obase = ((size_t)(b * T_ + c * 8)) * 64 + lane;
#pragma unroll
  for (int r = 0; r < 8; ++r) {
    const float4 xe = X[2 * r], xo = X[2 * r + 1];
    const float e0 = __expf(xe.x), e1 = __expf(xe.y), e2 = __expf(xe.z), e3 = __expf(xe.w);
    const float e4 = __expf(xo.x), e5 = __expf(xo.y), e6 = __expf(xo.z), e7 = __expf(xo.w);
    float s = ((e0 + e1) + (e2 + e3)) + ((e4 + e5) + (e6 + e7));
    DPPADD(s, 0x111, 0xf); DPPADD(s, 0x112, 0xf); DPPADD(s, 0x114, 0xf);
    DPPADD(s, 0x118, 0xf); DPPADD(s, 0x142, 0xa); DPPADD(s, 0x143, 0xc);
    const float sum = __int_as_float(__builtin_amdgcn_readlane(__float_as_int(s), 63));
    const float inv = 32.0f / sum;  // same x32 prescale as verified kernels
    float* sc = &scr[wid][r & 1][0];  // 2-slot alternation; wave-ordered LDS pipe
    *(float4*)(sc + 4 * lane) = make_float4(e0, e1, e2, e3);
    *(float4*)(sc + 256 + 4 * lane) = make_float4(e4, e5, e6, e7);
    asm volatile("s_waitcnt lgkmcnt(0)" ::: "memory");
    H4U p;
    p.h.x = (_Float16)(v0 ? sc[c4.x] * inv : 0.0f);  // LDS gather, conflict-cheap
    p.h.y = (_Float16)(v1 ? sc[c4.y] * inv : 0.0f);
    p.h.z = (_Float16)(v2 ? sc[c4.z] * inv : 0.0f);
    p.h.w = (_Float16)(v3 ? sc[c4.w] * inv : 0.0f);
    cull[obase + (size_t)r * 64] = p.u;  // plain L2-cached store
    if (lane == 0) bl[b * 2048 + c * 8 + r] = e0 * inv;  // blank prob (class 0)
  }
}

// ================== phase B: fwd/bwd block-float recursions ==================
__global__ __launch_bounds__(64) void krec(const int* __restrict__ lens,
                                           const int* __restrict__ targets,
                                           const unsigned long long* __restrict__ cull,
                                           const float* __restrict__ bl,
                                           float* __restrict__ AF, int* __restrict__ EF,
                                           float* __restrict__ DD, int* __restrict__ EB) {
  const int lane = threadIdx.x;
  __shared__ int cmp[256];
  const int b = blockIdx.x >> 1;
  const int dirb = blockIdx.x & 1;
  const int len = lens[b];
  const int rem = len & 7;
  const int nch = (len + 7) >> 3;
  const int Cf = nch >> 1;  // fwd owns chunks [0, Cf) (all full); bwd owns [Cf, nch)
  const int Ntot = dirb ? (nch - Cf) : Cf;
  const int c0v = dirb ? (nch - 1) : 0;
  const int dstep = dirb ? -1 : 1;
#define CHK(J) (c0v + dstep * (J))

  COMPACT(b);
  const int tl = base;
  const int4 c4 = *(const int4*)(&cmp[4 * lane]);

  const int cm1 = __shfl_up(c4.w, 1);
  const float m0 = (lane > 0 && c4.x != 0 && c4.x != cm1) ? 1.0f : 0.0f;
  const float m1 = (c4.y != 0 && c4.y != c4.x) ? 1.0f : 0.0f;
  const float m2 = (c4.z != 0 && c4.z != c4.y) ? 1.0f : 0.0f;
  const float m3 = (c4.w != 0 && c4.w != c4.z) ? 1.0f : 0.0f;
  const float m0n = dpp_shl1_f(m0);

  float a0 = 0.f, a1 = 0.f, a2 = 0.f, a3 = 0.f, a4 = 0.f, a5 = 0.f, a6 = 0.f, a7 = 0.f;
  int E = 0;
  float fac = 1.0f;
  if (!dirb) {
    if (lane == 0) a0 = 1.0f;  // chunk-0 step u=0 reproduces the alpha init
  } else {
    const int st = 2 * tl;  // gamma seed; first bwd step reproduces the init
    if (lane == (st >> 3)) {
      const int e = st & 7;
      a0 = (e == 0) ? 1.0f : 0.0f; a1 = (e == 1) ? 1.0f : 0.0f;
      a2 = (e == 2) ? 1.0f : 0.0f; a3 = (e == 3) ? 1.0f : 0.0f;
      a4 = (e == 4) ? 1.0f : 0.0f; a5 = (e == 5) ? 1.0f : 0.0f;
      a6 = (e == 6) ? 1.0f : 0.0f; a7 = (e == 7) ? 1.0f : 0.0f;
    }
  }

  unsigned long long LB0[8], LB1[8], LB2[8], LB3[8];
  float4 BLa0, BLb0, BLa1, BLb1, BLa2, BLb2, BLa3, BLb3;

#define LOADC(S, CIDX)                                                       \
  {                                                                          \
    const int c_ = (CIDX);                                                   \
    const unsigned long long* pp_ = cull + ((size_t)(b * T_ + c_ * 8)) * 64 + lane; \
    _Pragma("unroll") for (int u = 0; u < 8; ++u) LB##S[u] = pp_[(size_t)u * 64]; \
    const float* bf_ = bl + b * 2048 + c_ * 8;                               \
    BLa##S = *(const float4*)(bf_);                                          \
    BLb##S = *(const float4*)(bf_ + 4);                                      \
  }

#define PREFETCH(S)                                                          \
  {                                                                          \
    const int nx_ = i + 4;                                                   \
    if (nx_ < Ntot) LOADC(S, CHK(nx_));                                      \
  }

#define STEP8F(S)                                                            \
  {                                                                          \
    const float blv_[8] = {BLa##S.x, BLa##S.y, BLa##S.z, BLa##S.w,           \
                           BLb##S.x, BLb##S.y, BLb##S.z, BLb##S.w};          \
    _Pragma("unroll") for (int u = 0; u < 8; ++u) {                          \
      H4U q_; q_.u = LB##S[u];                                               \
      const float qx = (float)q_.h.x, qy = (float)q_.h.y;                    \
      const float qz = (float)q_.h.z, qw = (float)q_.h.w;                    \
      const float pbv = blv_[u];                                             \
      const float s1 = dpp_shr1_f(a7) * fac;  /* lane0 -> 0 */               \
      float n0 = (a0 + s1) * pbv;                                            \
      float n1 = fmaf(m0, s1, a0 + a1) * qx;                                 \
      float n2 = (a2 + a1) * pbv;                                            \
      float n3 = fmaf(m1, a1, a2 + a3) * qy;                                 \
      float n4 = (a4 + a3) * pbv;                                            \
      float n5 = fmaf(m2, a3, a4 + a5) * qz;                                 \
      float n6 = (a6 + a5) * pbv;                                            \
      float n7 = fmaf(m3, a5, a6 + a7) * qw;                                 \
      a0 = n0; a1 = n1; a2 = n2; a3 = n3;                                    \
      a4 = n4; a5 = n5; a6 = n6; a7 = n7;                                    \
    }                                                                        \
  }

#define STEP8B(S, UHI)                                                       \
  {                                                                          \
    const float blv_[8] = {BLa##S.x, BLa##S.y, BLa##S.z, BLa##S.w,           \
                           BLb##S.x, BLb##S.y, BLb##S.z, BLb##S.w};          \
    _Pragma("unroll") for (int u = 7; u >= 0; --u) {                         \
      if (u <= (UHI)) {                                                      \
        H4U q_; q_.u = LB##S[u];                                             \
        const float qx = (float)q_.h.x, qy = (float)q_.h.y;                  \
        const float qz = (float)q_.h.z, qw = (float)q_.h.w;                  \
        const float pbv = blv_[u];                                           \
        const float sa = dpp_shl1_f(a0) * fac;  /* lane63 -> 0 */            \
        const float sb = dpp_shl1_f(a1) * fac;                               \
        float n0 = (a0 + a1) * pbv;                                          \
        float n1 = fmaf(m1, a3, a1 + a2) * qx;                               \
        float n2 = (a2 + a3) * pbv;                                          \
        float n3 = fmaf(m2, a5, a3 + a4) * qy;                               \
        float n4 = (a4 + a5) * pbv;                                          \
        float n5 = fmaf(m3, a7, a5 + a6) * qz;                               \
        float n6 = (a6 + a7) * pbv;                                          \
        float n7 = fmaf(m0n, sb, a7 + sa) * qw;                              \
        a0 = n0; a1 = n1; a2 = n2; a3 = n3;                                  \
        a4 = n4; a5 = n5; a6 = n6; a7 = n7;                                  \
      }                                                                      \
    }                                                                        \
  }

#define RENORM_COMMON                                                        \
    const float mx = fmaxf(fmaxf(fmaxf(a0, a1), fmaxf(a2, a3)),              \
                           fmaxf(fmaxf(a4, a5), fmaxf(a6, a7)));             \
    const bool dead = (mx == 0.0f);                                          \
    int e_ = (int)((__float_as_uint(mx) >> 23) & 0xff) - 127;                \
    if (dead) e_ = 0;                                                        \
    const float sc_ = __int_as_float((unsigned)(127 - e_) << 23);            \
    a0 *= sc_; a1 *= sc_; a2 *= sc_; a3 *= sc_;                              \
    a4 *= sc_; a5 *= sc_; a6 *= sc_; a7 *= sc_;                              \
    const int En_ = E + e_;

#define RENORMF                                                              \
  {                                                                          \
    RENORM_COMMON                                                            \
    const int EnP_ = dpp_shr1_i(En_);                                        \
    E = dead ? EnP_ : En_;                                                   \
    const int Ep_ = dpp_shr1_i(E);                                           \
    const int d_ = Ep_ - E;                                                  \
    int dc_ = d_ < -126 ? -126 : (d_ > 126 ? 126 : d_);                      \
    fac = (d_ < -126) ? 0.0f : __int_as_float((unsigned)(dc_ + 127) << 23);  \
  }

#define RENORMB                                                              \
  {                                                                          \
    RENORM_COMMON                                                            \
    const int EnP_ = dpp_shl1_i(En_);                                        \
    E = dead ? EnP_ : En_;                                                   \
    const int Ep_ = dpp_shl1_i(E);                                           \
    const int d_ = Ep_ - E;                                                  \
    int dc_ = d_ < -126 ? -126 : (d_ > 126 ? 126 : d_);                      \
    fac = (d_ < -126) ? 0.0f : __int_as_float((unsigned)(dc_ + 127) << 23);  \
  }

  // prologue: 4-chunk register prefetch
  LOADC(0, CHK(0)); LOADC(1, CHK(1)); LOADC(2, CHK(2)); LOADC(3, CHK(3));

  if (!dirb) {
    for (int i = 0; i < Ntot; ++i) {
      switch (i & 3) {
        case 0: STEP8F(0); RENORMF; PREFETCH(0); break;
        case 1: STEP8F(1); RENORMF; PREFETCH(1); break;
        case 2: STEP8F(2); RENORMF; PREFETCH(2); break;
        default: STEP8F(3); RENORMF; PREFETCH(3); break;
      }
    }
    *(float4*)(AF + b * 512 + lane * 8) = make_float4(a0, a1, a2, a3);
    *(float4*)(AF + b * 512 + lane * 8 + 4) = make_float4(a4, a5, a6, a7);
    EF[b * 64 + lane] = E;
  } else {
    for (int i = 0; i < Ntot; ++i) {
      const int uh = (i == 0 && rem) ? (rem - 1) : 7;  // masked tail consumed first
      switch (i & 3) {
        case 0: STEP8B(0, uh); RENORMB; PREFETCH(0); break;
        case 1: STEP8B(1, uh); RENORMB; PREFETCH(1); break;
        case 2: STEP8B(2, uh); RENORMB; PREFETCH(2); break;
        default: STEP8B(3, uh); RENORMB; PREFETCH(3); break;
      }
    }
    // delta = one emission-less backward step of gamma_{8Cf}
    const float sa = dpp_shl1_f(a0) * fac;
    const float sb = dpp_shl1_f(a1) * fac;
    const float d0 = a0 + a1;
    const float d1 = fmaf(m1, a3, a1 + a2);
    const float d2 = a2 + a3;
    const float d3 = fmaf(m2, a5, a3 + a4);
    const float d4 = a4 + a5;
    const float d5 = fmaf(m3, a7, a5 + a6);
    const float d6 = a6 + a7;
    const float d7 = fmaf(m0n, sb, a7 + sa);
    *(float4*)(DD + b * 512 + lane * 8) = make_float4(d0, d1, d2, d3);
    *(float4*)(DD + b * 512 + lane * 8 + 4) = make_float4(d4, d5, d6, d7);
    EB[b * 64 + lane] = E;
  }
#undef LOADC
#undef PREFETCH
#undef STEP8F
#undef STEP8B
#undef RENORM_COMMON
#undef RENORMF
#undef RENORMB
#undef CHK
}

// ---- splice + final sum: out = -sum_b log( sum_s alpha[s]*delta[s] ) + len*ln(32) ----
__global__ __launch_bounds__(512) void kcomb(const int* __restrict__ lens,
                                             const float* __restrict__ AF,
                                             const int* __restrict__ EF,
                                             const float* __restrict__ DD,
                                             const int* __restrict__ EB,
                                             float* __restrict__ out) {
  const int wid = threadIdx.x >> 6;
  const int lane = threadIdx.x & 63;
  __shared__ float part[8];
  float acc = 0.0f;
#pragma unroll
  for (int q = 0; q < 8; ++q) {
    const int b = wid * 8 + q;
    const float4 f0 = *(const float4*)(AF + b * 512 + lane * 8);
    const float4 f1 = *(const float4*)(AF + b * 512 + lane * 8 + 4);
    const float4 g0 = *(const float4*)(DD + b * 512 + lane * 8);
    const float4 g1 = *(const float4*)(DD + b * 512 + lane * 8 + 4);
    const float dot = ((f0.x * g0.x + f0.y * g0.y) + (f0.z * g0.z + f0.w * g0.w)) +
                      ((f1.x * g1.x + f1.y * g1.y) + (f1.z * g1.z + f1.w * g1.w));
    const int Es = EF[b * 64 + lane] + EB[b * 64 + lane];
    const bool z = (dot == 0.0f);
    int Ek = z ? (-(1 << 28)) : Es;
#pragma unroll
    for (int off = 32; off; off >>= 1) {
      const int o = __shfl_xor(Ek, off);
      Ek = o > Ek ? o : Ek;
    }
    float v = z ? 0.0f : ldexpf(dot, Es - Ek);
#pragma unroll
    for (int off = 32; off; off >>= 1) v += __shfl_xor(v, off);
    const float ll = __logf(v) + (float)Ek * 0.69314718056f - (float)lens[b] * 3.46573590280f;
    acc -= ll;
  }
  if (lane == 0) part[wid] = acc;
  __syncthreads();
  if (threadIdx.x == 0) {
    float s = ((part[0] + part[1]) + (part[2] + part[3])) +
              ((part[4] + part[5]) + (part[6] + part[7]));
    out[0] = s;
  }
}

extern "C" void kernel_launch(void* const* d_in, const int* in_sizes, int n_in,
                              void* d_out, int out_size, void* d_ws, size_t ws_size,
                              hipStream_t stream) {
  const float* logits = (const float*)d_in[0];     // [B,T,V] fp32 — read-only
  const int* input_lengths = (const int*)d_in[1];  // [B]
  const int* targets = (const int*)d_in[2];        // [B,L]
  float* out = (float*)d_out;                      // [1]
  // ws layout (bytes): compact fp16 [B][T][256] = 65,536,000; blank f32 [B][2048]
  // = 524,288; (gap); AF/EF/DD/EB.
  unsigned long long* cull = (unsigned long long*)d_ws;
  float* bl = (float*)((char*)d_ws + 65536000);
  float* AF = (float*)((char*)d_ws + 66125824);
  int* EF = (int*)((char*)d_ws + 66256896);
  float* DD = (float*)((char*)d_ws + 66273280);
  int* EB = (int*)((char*)d_ws + 66404352);
  (void)in_sizes; (void)n_in; (void)out_size; (void)ws_size;

  kprob<<<B_ * NJB, 256, 0, stream>>>(logits, input_lengths, targets, cull, bl);
  krec<<<2 * B_, 64, 0, stream>>>(input_lengths, targets, cull, bl, AF, EF, DD, EB);
  kcomb<<<1, 512, 0, stream>>>(input_lengths, AF, EF, DD, EB, out);
}